// Round 21
// baseline (110.627 us; speedup 1.0000x reference)
//
#include <hip/hip_runtime.h>

#define NN 10000
#define NE 640000
#define D 128
#define NC 40
#define CAP 128
#define NBKT 313      // dst>>5 buckets (32 nodes each)
#define NBIN 157      // binning blocks (4096 edges each)
#define DEPTH 24      // LDS bin depth
#define GR 8          // cursor/slab groups
#define BCAPG 352     // per (bucket,group) capacity

typedef unsigned short u16;
typedef unsigned int u32;
typedef short bf16x8 __attribute__((ext_vector_type(8)));
typedef float f32x4v __attribute__((ext_vector_type(4)));

__device__ __forceinline__ float bf2f(u16 u) { return __uint_as_float(((u32)u) << 16); }
__device__ __forceinline__ u16 f2bf(float f) {
    u32 u = __float_as_uint(f);
    u += 0x7fff + ((u >> 16) & 1);  // RNE
    return (u16)(u >> 16);
}
__device__ __forceinline__ void upadd(u32 w, float& a, float& b) {
    a += __uint_as_float(w << 16);
    b += __uint_as_float(w & 0xffff0000u);
}

// ---------- prep: zero gcur padded region (0..39) | cvt W0,W1,W2 (40..63) ----------
__global__ __launch_bounds__(256) void prep_kernel(uint4* __restrict__ gcur4,
        const float* __restrict__ W0, const float* __restrict__ W1, const float* __restrict__ W2,
        u16* __restrict__ whi, u16* __restrict__ wlo) {
    int b = blockIdx.x, t = threadIdx.x;
    if (b < 40) {
        int i = b * 256 + t;
        if (i < GR * NBKT * 4) gcur4[i] = make_uint4(0u, 0u, 0u, 0u);
    } else {
        int idx = (b - 40) * 2048 + t * 8;   // 0..49151
        int wi = idx >> 14, off = idx & 16383;
        const float* W = (wi == 0) ? W0 : ((wi == 1) ? W1 : W2);
        float4 v0 = *reinterpret_cast<const float4*>(W + off);
        float4 v1 = *reinterpret_cast<const float4*>(W + off + 4);
        float wv[8] = {v0.x, v0.y, v0.z, v0.w, v1.x, v1.y, v1.z, v1.w};
        u16 ho[8], lo[8];
        #pragma unroll
        for (int j = 0; j < 8; j++) {
            u16 h = f2bf(wv[j]);
            ho[j] = h;
            lo[j] = f2bf(wv[j] - bf2f(h));
        }
        *reinterpret_cast<uint4*>(whi + idx) = *reinterpret_cast<uint4*>(ho);
        *reinterpret_cast<uint4*>(wlo + idx) = *reinterpret_cast<uint4*>(lo);
    }
}

// ---------- phase A: bin edges (0..156, grouped cursors) | gemm0 x*W0^T -> gbA (157..469) ----------
__global__ __launch_bounds__(256) void phaseA(const float* __restrict__ x,
        const int* __restrict__ src, const int* __restrict__ dst,
        const u16* __restrict__ whi, const u16* __restrict__ wlo,
        int* __restrict__ gcur, u32* __restrict__ gbucket, u16* __restrict__ G) {
    __shared__ union {
        struct { u32 bin[NBKT][DEPTH]; int bcnt[NBKT]; int gbase[NBKT]; u32 ovf[128][2]; int ocnt; } a;
        u16 Gs[32 * 128];
    } sm;
    int b = blockIdx.x, t = threadIdx.x;
    if (b < NBIN) {
        int g = b & (GR - 1);
        for (int i = t; i < NBKT; i += 256) sm.a.bcnt[i] = 0;
        if (t == 0) sm.a.ocnt = 0;
        __syncthreads();
        #pragma unroll
        for (int rep = 0; rep < 4; rep++) {
            int e0 = b * 4096 + rep * 1024 + t * 4;
            if (e0 < NE) {
                int4 d4 = *reinterpret_cast<const int4*>(dst + e0);
                int4 s4 = *reinterpret_cast<const int4*>(src + e0);
                int dd[4] = {d4.x, d4.y, d4.z, d4.w};
                int ss[4] = {s4.x, s4.y, s4.z, s4.w};
                #pragma unroll
                for (int i = 0; i < 4; i++) {
                    int bk = dd[i] >> 5;
                    u32 entry = ((u32)(dd[i] & 31) << 16) | (u32)ss[i];
                    int pos = atomicAdd(&sm.a.bcnt[bk], 1);
                    if (pos < DEPTH) sm.a.bin[bk][pos] = entry;
                    else {
                        int o = atomicAdd(&sm.a.ocnt, 1);
                        if (o < 128) { sm.a.ovf[o][0] = ((u32)bk << 16) | (u32)pos; sm.a.ovf[o][1] = entry; }
                    }
                }
            }
        }
        __syncthreads();
        for (int i = t; i < NBKT; i += 256) {
            int n = sm.a.bcnt[i];
            sm.a.gbase[i] = n ? atomicAdd(&gcur[(g * NBKT + i) * 16], n) : 0;
        }
        __syncthreads();
        for (int idx = t; idx < NBKT * DEPTH; idx += 256) {
            int bk = idx / DEPTH, j = idx - bk * DEPTH;
            int n = sm.a.bcnt[bk];
            if (j < (n > DEPTH ? DEPTH : n)) {
                int p = sm.a.gbase[bk] + j;
                if (p < BCAPG) gbucket[((size_t)bk * GR + g) * BCAPG + p] = sm.a.bin[bk][j];
            }
        }
        int oc = sm.a.ocnt; if (oc > 128) oc = 128;
        for (int i = t; i < oc; i += 256) {
            int bk = (int)(sm.a.ovf[i][0] >> 16);
            int pos = (int)(sm.a.ovf[i][0] & 0xffff);
            int p = sm.a.gbase[bk] + pos;
            if (p >= 0 && p < BCAPG) gbucket[((size_t)bk * GR + g) * BCAPG + p] = sm.a.ovf[i][1];
        }
    } else {
        // gemm0: 32-node tile; A = x (fp32, cvt in-reg); B = whi/wlo bf16 direct from L2
        int nb0 = (b - NBIN) * 32;
        int wid = t >> 6, l = t & 63;
        int m = l & 15, gq = l >> 4;
        int mt = wid & 1, nh = wid >> 1;
        int nodeA = nb0 + mt * 16 + m;
        if (nodeA >= NN) nodeA = NN - 1;
        const float* xr = x + (size_t)nodeA * 128;
        bf16x8 afr[4];
        #pragma unroll
        for (int ks = 0; ks < 4; ks++) {
            float4 a0 = *reinterpret_cast<const float4*>(xr + ks * 32 + gq * 8);
            float4 a1 = *reinterpret_cast<const float4*>(xr + ks * 32 + gq * 8 + 4);
            float av[8] = {a0.x, a0.y, a0.z, a0.w, a1.x, a1.y, a1.z, a1.w};
            union { uint4 u; bf16x8 v; } ca;
            u32 ap[4];
            #pragma unroll
            for (int j = 0; j < 4; j++)
                ap[j] = (u32)f2bf(av[2 * j]) | ((u32)f2bf(av[2 * j + 1]) << 16);
            ca.u = make_uint4(ap[0], ap[1], ap[2], ap[3]);
            afr[ks] = ca.v;
        }
        f32x4v acc[4];
        #pragma unroll
        for (int nt = 0; nt < 4; nt++) acc[nt] = (f32x4v){0.f, 0.f, 0.f, 0.f};
        #pragma unroll
        for (int ks = 0; ks < 4; ks++) {
            #pragma unroll
            for (int nt = 0; nt < 4; nt++) {
                int n = nh * 64 + nt * 16 + m;
                bf16x8 bh = *reinterpret_cast<const bf16x8*>(whi + (size_t)n * 128 + ks * 32 + gq * 8);
                bf16x8 bl = *reinterpret_cast<const bf16x8*>(wlo + (size_t)n * 128 + ks * 32 + gq * 8);
                acc[nt] = __builtin_amdgcn_mfma_f32_16x16x32_bf16(afr[ks], bh, acc[nt], 0, 0, 0);
                acc[nt] = __builtin_amdgcn_mfma_f32_16x16x32_bf16(afr[ks], bl, acc[nt], 0, 0, 0);
            }
        }
        #pragma unroll
        for (int nt = 0; nt < 4; nt++) {
            #pragma unroll
            for (int j = 0; j < 4; j++) {
                int mm = mt * 16 + gq * 4 + j;
                int n = nh * 64 + nt * 16 + m;
                sm.Gs[mm * 128 + (n ^ ((mm & 7) << 4))] = f2bf(acc[nt][j]);
            }
        }
        __syncthreads();
        #pragma unroll
        for (int i = 0; i < 2; i++) {
            int c = t + i * 256;
            int mm = c >> 4, n0 = (c & 15) * 8;
            int node = nb0 + mm;
            if (node < NN) {
                uint4 v = *reinterpret_cast<const uint4*>(&sm.Gs[mm * 128 + (n0 ^ ((mm & 7) << 4))]);
                *reinterpret_cast<uint4*>(G + (size_t)node * 128 + n0) = v;
            }
        }
    }
}

// ---------- F_l: fused [CSR-build (FIRST) | csr-read] aggrelu -> gemm_{l+1} or classifier ----------
template<bool FIRST, bool LAST>
__global__ __launch_bounds__(1024) void fuse_kernel(
        const u16* __restrict__ gin, int* __restrict__ cnt, u16* __restrict__ csr,
        const int* __restrict__ gcur, const u32* __restrict__ gbucket,
        const float* __restrict__ bias, const float* __restrict__ pd,
        const u16* __restrict__ wh, const u16* __restrict__ wl_, u16* __restrict__ gout,
        const float* __restrict__ Wl, const float* __restrict__ bl, float* __restrict__ out) {
    __shared__ u16 nbr[16][128];                                            // 4 KB, per-node ids
    __shared__ int scnt[16];
    __shared__ union {
        u16 A[16 * 128];                                                    // 4 KB (Gs overlays)
        struct { float WlS[NC * 129]; float rows[16 * D]; float blS[NC]; } c;  // ~29 KB
    } sm;
    const int t = threadIdx.x, wid = t >> 6, ln = t & 63;
    const int q = ln >> 4, fq = ln & 15, fo8 = fq << 3;
    const int nb0 = blockIdx.x * 16;   // 625 blocks x 16 nodes = 10000 exactly
    const int node = nb0 + wid;        // one node per wave

    if (LAST) {
        for (int i = t; i < NC * D; i += 1024) sm.c.WlS[(i >> 7) * 129 + (i & 127)] = Wl[i];
        if (t < NC) sm.c.blS[t] = bl[t];
    }

    int c_;
    if (FIRST) {
        int bk = blockIdx.x >> 1, half = blockIdx.x & 1;
        if (t < 16) scnt[t] = 0;
        __syncthreads();
        for (int g = 0; g < GR; g++) {
            int total = gcur[(g * NBKT + bk) * 16];
            if (total > BCAPG) total = BCAPG;
            const u32* gb = gbucket + ((size_t)bk * GR + g) * BCAPG;
            for (int i = t; i < total; i += 1024) {
                u32 e = gb[i];
                int dl = (int)((e >> 16) & 31);
                if ((dl >> 4) == half) {
                    int pos = atomicAdd(&scnt[dl & 15], 1);
                    if (pos < CAP) nbr[dl & 15][pos] = (u16)(e & 0xffff);
                }
            }
        }
        __syncthreads();
        {
            int row = t >> 6, dw = t & 63;
            reinterpret_cast<u32*>(csr + ((size_t)(nb0 + row) << 7))[dw] =
                reinterpret_cast<const u32*>(&nbr[row][0])[dw];
            if (t < 16) cnt[nb0 + t] = scnt[t] > CAP ? CAP : scnt[t];
        }
        c_ = scnt[wid];
        if (c_ > CAP) c_ = CAP;
    } else {
        c_ = cnt[node];
        if (c_ > CAP) c_ = CAP;
        *reinterpret_cast<u32*>(&nbr[wid][ln << 1]) =
            *reinterpret_cast<const u32*>(csr + ((size_t)node << 7) + (ln << 1));
    }

    // ---- gather: 32 rows / iteration; each quarter owns rows {b0..b0+3, b0+16..b0+19} ----
    float va[8] = {0.f, 0.f, 0.f, 0.f, 0.f, 0.f, 0.f, 0.f};
    if (q == 0) {  // self term
        uint4 v = *reinterpret_cast<const uint4*>(gin + ((size_t)node << 7) + fo8);
        upadd(v.x, va[0], va[1]); upadd(v.y, va[2], va[3]);
        upadd(v.z, va[4], va[5]); upadd(v.w, va[6], va[7]);
    }
    int iters = (c_ + 31) >> 5;
    for (int i = 0; i < iters; i++) {
        int b0 = (i << 5) + (q << 2);
        int b1 = b0 + 16;
        ushort4 ia = *reinterpret_cast<const ushort4*>(&nbr[wid][b0]);
        ushort4 ib = *reinterpret_cast<const ushort4*>(&nbr[wid][b1]);
        int id0 = (b0 + 0 < c_) ? (int)ia.x : node;
        int id1 = (b0 + 1 < c_) ? (int)ia.y : node;
        int id2 = (b0 + 2 < c_) ? (int)ia.z : node;
        int id3 = (b0 + 3 < c_) ? (int)ia.w : node;
        int id4 = (b1 + 0 < c_) ? (int)ib.x : node;
        int id5 = (b1 + 1 < c_) ? (int)ib.y : node;
        int id6 = (b1 + 2 < c_) ? (int)ib.z : node;
        int id7 = (b1 + 3 < c_) ? (int)ib.w : node;
        uint4 v0 = *reinterpret_cast<const uint4*>(gin + ((size_t)id0 << 7) + fo8);
        uint4 v1 = *reinterpret_cast<const uint4*>(gin + ((size_t)id1 << 7) + fo8);
        uint4 v2 = *reinterpret_cast<const uint4*>(gin + ((size_t)id2 << 7) + fo8);
        uint4 v3 = *reinterpret_cast<const uint4*>(gin + ((size_t)id3 << 7) + fo8);
        uint4 v4 = *reinterpret_cast<const uint4*>(gin + ((size_t)id4 << 7) + fo8);
        uint4 v5 = *reinterpret_cast<const uint4*>(gin + ((size_t)id5 << 7) + fo8);
        uint4 v6 = *reinterpret_cast<const uint4*>(gin + ((size_t)id6 << 7) + fo8);
        uint4 v7 = *reinterpret_cast<const uint4*>(gin + ((size_t)id7 << 7) + fo8);
        if (b0 + 0 < c_) { upadd(v0.x, va[0], va[1]); upadd(v0.y, va[2], va[3]); upadd(v0.z, va[4], va[5]); upadd(v0.w, va[6], va[7]); }
        if (b0 + 1 < c_) { upadd(v1.x, va[0], va[1]); upadd(v1.y, va[2], va[3]); upadd(v1.z, va[4], va[5]); upadd(v1.w, va[6], va[7]); }
        if (b0 + 2 < c_) { upadd(v2.x, va[0], va[1]); upadd(v2.y, va[2], va[3]); upadd(v2.z, va[4], va[5]); upadd(v2.w, va[6], va[7]); }
        if (b0 + 3 < c_) { upadd(v3.x, va[0], va[1]); upadd(v3.y, va[2], va[3]); upadd(v3.z, va[4], va[5]); upadd(v3.w, va[6], va[7]); }
        if (b1 + 0 < c_) { upadd(v4.x, va[0], va[1]); upadd(v4.y, va[2], va[3]); upadd(v4.z, va[4], va[5]); upadd(v4.w, va[6], va[7]); }
        if (b1 + 1 < c_) { upadd(v5.x, va[0], va[1]); upadd(v5.y, va[2], va[3]); upadd(v5.z, va[4], va[5]); upadd(v5.w, va[6], va[7]); }
        if (b1 + 2 < c_) { upadd(v6.x, va[0], va[1]); upadd(v6.y, va[2], va[3]); upadd(v6.z, va[4], va[5]); upadd(v6.w, va[6], va[7]); }
        if (b1 + 3 < c_) { upadd(v7.x, va[0], va[1]); upadd(v7.y, va[2], va[3]); upadd(v7.z, va[4], va[5]); upadd(v7.w, va[6], va[7]); }
    }
    #pragma unroll
    for (int j = 0; j < 8; j++) {
        va[j] += __shfl_xor(va[j], 16);
        va[j] += __shfl_xor(va[j], 32);
    }
    if (ln < 16) {
        float4 bv0 = *reinterpret_cast<const float4*>(bias + fo8);
        float4 bv1 = *reinterpret_cast<const float4*>(bias + fo8 + 4);
        float4 mv0 = *reinterpret_cast<const float4*>(pd + fo8);
        float4 mv1 = *reinterpret_cast<const float4*>(pd + fo8 + 4);
        float bb[8] = {bv0.x, bv0.y, bv0.z, bv0.w, bv1.x, bv1.y, bv1.z, bv1.w};
        float mm[8] = {mv0.x, mv0.y, mv0.z, mv0.w, mv1.x, mv1.y, mv1.z, mv1.w};
        float r[8];
        #pragma unroll
        for (int j = 0; j < 8; j++) {
            float mk = fminf(fmaxf(mm[j], 0.f), 1.f);
            r[j] = fmaxf(va[j] + bb[j], 0.f) * mk;
        }
        if (LAST) {
            #pragma unroll
            for (int j = 0; j < 8; j++) sm.c.rows[wid * D + fo8 + j] = r[j];
        } else {
            u32 p0 = (u32)f2bf(r[0]) | ((u32)f2bf(r[1]) << 16);
            u32 p1 = (u32)f2bf(r[2]) | ((u32)f2bf(r[3]) << 16);
            u32 p2 = (u32)f2bf(r[4]) | ((u32)f2bf(r[5]) << 16);
            u32 p3 = (u32)f2bf(r[6]) | ((u32)f2bf(r[7]) << 16);
            *reinterpret_cast<uint4*>(&sm.A[wid * 128 + ((fq ^ (wid & 7)) << 3)]) =
                make_uint4(p0, p1, p2, p3);
        }
    }
    __syncthreads();

    if (LAST) {
        if (t < 16 * NC) {
            int n = t / NC, c = t - n * NC;
            const float* rr = &sm.c.rows[n * D];
            const float* wr = &sm.c.WlS[c * 129];
            float acc = sm.c.blS[c];
            #pragma unroll 8
            for (int k = 0; k < D; k++) acc = fmaf(rr[k], wr[k], acc);
            out[(size_t)(nb0 + n) * NC + c] = acc;
        }
        return;
    }

    // ---- gemm: A (16x128, LDS) x W^T (B-fragments direct from L2) ----
    int m = ln & 15, gq = ln >> 4;
    bf16x8 afr[4];
    if (wid < 8) {
        #pragma unroll
        for (int ks = 0; ks < 4; ks++) {
            int chunk = gq + ks * 4;
            afr[ks] = *reinterpret_cast<const bf16x8*>(&sm.A[m * 128 + ((chunk ^ (m & 7)) << 3)]);
        }
    }
    __syncthreads();  // all afr loaded before A is overlaid by Gs
    if (wid < 8) {
        f32x4v acc = (f32x4v){0.f, 0.f, 0.f, 0.f};
        int n = wid * 16 + m;
        const u16* whp = wh + (size_t)n * 128;
        const u16* wlp = wl_ + (size_t)n * 128;
        #pragma unroll
        for (int ks = 0; ks < 4; ks++) {
            bf16x8 bh = *reinterpret_cast<const bf16x8*>(whp + ks * 32 + gq * 8);
            bf16x8 bl = *reinterpret_cast<const bf16x8*>(wlp + ks * 32 + gq * 8);
            acc = __builtin_amdgcn_mfma_f32_16x16x32_bf16(afr[ks], bh, acc, 0, 0, 0);
            acc = __builtin_amdgcn_mfma_f32_16x16x32_bf16(afr[ks], bl, acc, 0, 0, 0);
        }
        u16* Gs = sm.A;  // overlay
        #pragma unroll
        for (int j = 0; j < 4; j++) {
            int mm = gq * 4 + j;
            Gs[mm * 128 + (n ^ ((mm & 7) << 4))] = f2bf(acc[j]);
        }
    }
    __syncthreads();
    if (t < 256) {
        const u16* Gs = sm.A;
        int mm = t >> 4, n0 = (t & 15) * 8;
        uint4 v = *reinterpret_cast<const uint4*>(&Gs[mm * 128 + (n0 ^ ((mm & 7) << 4))]);
        *reinterpret_cast<uint4*>(gout + (size_t)(nb0 + mm) * 128 + n0) = v;
    }
}

// ---------- launch ----------
// ATTRIBUTION ROUND: (prep, phaseA) dispatched twice — idempotent as a pair
// (prep re-zeroes gcur; phaseA re-bins same slab content + same gemm0 output).
// Delta vs R20 total isolates prep+phaseA+2 gaps.
extern "C" void kernel_launch(void* const* d_in, const int* in_sizes, int n_in,
                              void* d_out, int out_size, void* d_ws, size_t ws_size,
                              hipStream_t stream) {
    const float* x  = (const float*)d_in[0];
    const int*   ei = (const int*)d_in[1];
    const float* W0 = (const float*)d_in[2];
    const float* b0 = (const float*)d_in[3];
    const float* W1 = (const float*)d_in[4];
    const float* b1 = (const float*)d_in[5];
    const float* W2 = (const float*)d_in[6];
    const float* b2 = (const float*)d_in[7];
    const float* pd = (const float*)d_in[8];
    const float* Wl = (const float*)d_in[9];
    const float* bl = (const float*)d_in[10];

    char* ws = (char*)d_ws;
    int* cnt     = (int*)ws;                    //     40,960 B
    u16* csr     = (u16*)(ws + 40960);          //  2,560,000 B
    u16* gbA     = (u16*)(ws + 2600960);        //  2,560,000 B
    u16* gbB     = (u16*)(ws + 5160960);        //  2,560,000 B
    u32* gbucket = (u32*)(ws + 7720960);        //  3,525,632 B (live until F0 completes)
    int* gcur    = (int*)(ws + 11246592);       //    160,256 B (8*313 cursors, 64B-padded)
    u16* whi     = (u16*)(ws + 11406848);       //     98,304 B
    u16* wlo     = (u16*)(ws + 11505152);       //     98,304 B -> total ~11.6 MB

    const int* src = ei;
    const int* dst = ei + NE;

    prep_kernel<<<64, 256, 0, stream>>>((uint4*)gcur, W0, W1, W2, whi, wlo);
    phaseA<<<NBIN + 313, 256, 0, stream>>>(x, src, dst, whi, wlo, gcur, gbucket, gbA);
    prep_kernel<<<64, 256, 0, stream>>>((uint4*)gcur, W0, W1, W2, whi, wlo);
    phaseA<<<NBIN + 313, 256, 0, stream>>>(x, src, dst, whi, wlo, gcur, gbucket, gbA);
    fuse_kernel<true, false><<<625, 1024, 0, stream>>>(gbA, cnt, csr, gcur, gbucket, b0, pd,
                                                       whi + 16384, wlo + 16384, gbB,
                                                       nullptr, nullptr, nullptr);
    fuse_kernel<false, false><<<625, 1024, 0, stream>>>(gbB, cnt, csr, nullptr, nullptr, b1, pd,
                                                        whi + 32768, wlo + 32768, gbA,
                                                        nullptr, nullptr, nullptr);
    fuse_kernel<false, true><<<625, 1024, 0, stream>>>(gbA, cnt, csr, nullptr, nullptr, b2, pd,
                                                       nullptr, nullptr, nullptr,
                                                       Wl, bl, (float*)d_out);
}

// Round 22
// 96.908 us; speedup vs baseline: 1.1416x; 1.1416x over previous
//
#include <hip/hip_runtime.h>

#define NN 10000
#define NE 640000
#define D 128
#define NC 40
#define CAP 128
#define NBKT 313      // dst>>5 buckets (32 nodes each)
#define NBIN 157      // binning blocks (4096 edges each)
#define DEPTH 24      // LDS bin depth
#define GR 8          // cursor/slab groups
#define BCAPG 352     // per (bucket,group) capacity

typedef unsigned short u16;
typedef unsigned int u32;
typedef short bf16x8 __attribute__((ext_vector_type(8)));
typedef float f32x4v __attribute__((ext_vector_type(4)));

__device__ __forceinline__ float bf2f(u16 u) { return __uint_as_float(((u32)u) << 16); }
__device__ __forceinline__ u16 f2bf(float f) {
    u32 u = __float_as_uint(f);
    u += 0x7fff + ((u >> 16) & 1);  // RNE
    return (u16)(u >> 16);
}
__device__ __forceinline__ void upadd(u32 w, float& a, float& b) {
    a += __uint_as_float(w << 16);
    b += __uint_as_float(w & 0xffff0000u);
}

// ---------- prep: zero gcur padded region (0..39) | cvt W0,W1,W2 (40..63) ----------
__global__ __launch_bounds__(256) void prep_kernel(uint4* __restrict__ gcur4,
        const float* __restrict__ W0, const float* __restrict__ W1, const float* __restrict__ W2,
        u16* __restrict__ whi, u16* __restrict__ wlo) {
    int b = blockIdx.x, t = threadIdx.x;
    if (b < 40) {
        int i = b * 256 + t;
        if (i < GR * NBKT * 4) gcur4[i] = make_uint4(0u, 0u, 0u, 0u);
    } else {
        int idx = (b - 40) * 2048 + t * 8;   // 0..49151
        int wi = idx >> 14, off = idx & 16383;
        const float* W = (wi == 0) ? W0 : ((wi == 1) ? W1 : W2);
        float4 v0 = *reinterpret_cast<const float4*>(W + off);
        float4 v1 = *reinterpret_cast<const float4*>(W + off + 4);
        float wv[8] = {v0.x, v0.y, v0.z, v0.w, v1.x, v1.y, v1.z, v1.w};
        u16 ho[8], lo[8];
        #pragma unroll
        for (int j = 0; j < 8; j++) {
            u16 h = f2bf(wv[j]);
            ho[j] = h;
            lo[j] = f2bf(wv[j] - bf2f(h));
        }
        *reinterpret_cast<uint4*>(whi + idx) = *reinterpret_cast<uint4*>(ho);
        *reinterpret_cast<uint4*>(wlo + idx) = *reinterpret_cast<uint4*>(lo);
    }
}

// ---------- phase A: bin edges (0..156, grouped cursors) | gemm0 x*W0^T -> gbA (157..469) ----------
__global__ __launch_bounds__(256) void phaseA(const float* __restrict__ x,
        const int* __restrict__ src, const int* __restrict__ dst,
        const u16* __restrict__ whi, const u16* __restrict__ wlo,
        int* __restrict__ gcur, u32* __restrict__ gbucket, u16* __restrict__ G) {
    __shared__ union {
        struct { u32 bin[NBKT][DEPTH]; int bcnt[NBKT]; int gbase[NBKT]; u32 ovf[128][2]; int ocnt; } a;
        u16 Gs[32 * 128];
    } sm;
    int b = blockIdx.x, t = threadIdx.x;
    if (b < NBIN) {
        int g = b & (GR - 1);
        for (int i = t; i < NBKT; i += 256) sm.a.bcnt[i] = 0;
        if (t == 0) sm.a.ocnt = 0;
        __syncthreads();
        #pragma unroll
        for (int rep = 0; rep < 4; rep++) {
            int e0 = b * 4096 + rep * 1024 + t * 4;
            if (e0 < NE) {
                int4 d4 = *reinterpret_cast<const int4*>(dst + e0);
                int4 s4 = *reinterpret_cast<const int4*>(src + e0);
                int dd[4] = {d4.x, d4.y, d4.z, d4.w};
                int ss[4] = {s4.x, s4.y, s4.z, s4.w};
                #pragma unroll
                for (int i = 0; i < 4; i++) {
                    int bk = dd[i] >> 5;
                    u32 entry = ((u32)(dd[i] & 31) << 16) | (u32)ss[i];
                    int pos = atomicAdd(&sm.a.bcnt[bk], 1);
                    if (pos < DEPTH) sm.a.bin[bk][pos] = entry;
                    else {
                        int o = atomicAdd(&sm.a.ocnt, 1);
                        if (o < 128) { sm.a.ovf[o][0] = ((u32)bk << 16) | (u32)pos; sm.a.ovf[o][1] = entry; }
                    }
                }
            }
        }
        __syncthreads();
        for (int i = t; i < NBKT; i += 256) {
            int n = sm.a.bcnt[i];
            sm.a.gbase[i] = n ? atomicAdd(&gcur[(g * NBKT + i) * 16], n) : 0;
        }
        __syncthreads();
        for (int idx = t; idx < NBKT * DEPTH; idx += 256) {
            int bk = idx / DEPTH, j = idx - bk * DEPTH;
            int n = sm.a.bcnt[bk];
            if (j < (n > DEPTH ? DEPTH : n)) {
                int p = sm.a.gbase[bk] + j;
                if (p < BCAPG) gbucket[((size_t)bk * GR + g) * BCAPG + p] = sm.a.bin[bk][j];
            }
        }
        int oc = sm.a.ocnt; if (oc > 128) oc = 128;
        for (int i = t; i < oc; i += 256) {
            int bk = (int)(sm.a.ovf[i][0] >> 16);
            int pos = (int)(sm.a.ovf[i][0] & 0xffff);
            int p = sm.a.gbase[bk] + pos;
            if (p >= 0 && p < BCAPG) gbucket[((size_t)bk * GR + g) * BCAPG + p] = sm.a.ovf[i][1];
        }
    } else {
        // gemm0: 32-node tile; A = x (fp32, cvt in-reg); B = whi/wlo bf16 direct from L2
        int nb0 = (b - NBIN) * 32;
        int wid = t >> 6, l = t & 63;
        int m = l & 15, gq = l >> 4;
        int mt = wid & 1, nh = wid >> 1;
        int nodeA = nb0 + mt * 16 + m;
        if (nodeA >= NN) nodeA = NN - 1;
        const float* xr = x + (size_t)nodeA * 128;
        bf16x8 afr[4];
        #pragma unroll
        for (int ks = 0; ks < 4; ks++) {
            float4 a0 = *reinterpret_cast<const float4*>(xr + ks * 32 + gq * 8);
            float4 a1 = *reinterpret_cast<const float4*>(xr + ks * 32 + gq * 8 + 4);
            float av[8] = {a0.x, a0.y, a0.z, a0.w, a1.x, a1.y, a1.z, a1.w};
            union { uint4 u; bf16x8 v; } ca;
            u32 ap[4];
            #pragma unroll
            for (int j = 0; j < 4; j++)
                ap[j] = (u32)f2bf(av[2 * j]) | ((u32)f2bf(av[2 * j + 1]) << 16);
            ca.u = make_uint4(ap[0], ap[1], ap[2], ap[3]);
            afr[ks] = ca.v;
        }
        f32x4v acc[4];
        #pragma unroll
        for (int nt = 0; nt < 4; nt++) acc[nt] = (f32x4v){0.f, 0.f, 0.f, 0.f};
        #pragma unroll
        for (int ks = 0; ks < 4; ks++) {
            #pragma unroll
            for (int nt = 0; nt < 4; nt++) {
                int n = nh * 64 + nt * 16 + m;
                bf16x8 bh = *reinterpret_cast<const bf16x8*>(whi + (size_t)n * 128 + ks * 32 + gq * 8);
                bf16x8 bl = *reinterpret_cast<const bf16x8*>(wlo + (size_t)n * 128 + ks * 32 + gq * 8);
                acc[nt] = __builtin_amdgcn_mfma_f32_16x16x32_bf16(afr[ks], bh, acc[nt], 0, 0, 0);
                acc[nt] = __builtin_amdgcn_mfma_f32_16x16x32_bf16(afr[ks], bl, acc[nt], 0, 0, 0);
            }
        }
        #pragma unroll
        for (int nt = 0; nt < 4; nt++) {
            #pragma unroll
            for (int j = 0; j < 4; j++) {
                int mm = mt * 16 + gq * 4 + j;
                int n = nh * 64 + nt * 16 + m;
                sm.Gs[mm * 128 + (n ^ ((mm & 7) << 4))] = f2bf(acc[nt][j]);
            }
        }
        __syncthreads();
        #pragma unroll
        for (int i = 0; i < 2; i++) {
            int c = t + i * 256;
            int mm = c >> 4, n0 = (c & 15) * 8;
            int node = nb0 + mm;
            if (node < NN) {
                uint4 v = *reinterpret_cast<const uint4*>(&sm.Gs[mm * 128 + (n0 ^ ((mm & 7) << 4))]);
                *reinterpret_cast<uint4*>(G + (size_t)node * 128 + n0) = v;
            }
        }
    }
}

// ---------- F_l: fused [CSR-build (FIRST) | csr-read] aggrelu -> gemm_{l+1} or classifier ----------
template<bool FIRST, bool LAST>
__global__ __launch_bounds__(1024) void fuse_kernel(
        const u16* __restrict__ gin, int* __restrict__ cnt, u16* __restrict__ csr,
        const int* __restrict__ gcur, const u32* __restrict__ gbucket,
        const float* __restrict__ bias, const float* __restrict__ pd,
        const u16* __restrict__ wh, const u16* __restrict__ wl_, u16* __restrict__ gout,
        const float* __restrict__ Wl, const float* __restrict__ bl, float* __restrict__ out) {
    __shared__ u16 nbr[16][128];                                            // 4 KB, per-node ids
    __shared__ int scnt[16];
    __shared__ union {
        u16 A[16 * 128];                                                    // 4 KB (Gs overlays)
        struct { float WlS[NC * 129]; float rows[16 * D]; float blS[NC]; } c;  // ~29 KB
    } sm;
    const int t = threadIdx.x, wid = t >> 6, ln = t & 63;
    const int q = ln >> 4, fq = ln & 15, fo8 = fq << 3;
    const int nb0 = blockIdx.x * 16;   // 625 blocks x 16 nodes = 10000 exactly
    const int node = nb0 + wid;        // one node per wave

    if (LAST) {
        for (int i = t; i < NC * D; i += 1024) sm.c.WlS[(i >> 7) * 129 + (i & 127)] = Wl[i];
        if (t < NC) sm.c.blS[t] = bl[t];
    }

    int c_;
    if (FIRST) {
        int bk = blockIdx.x >> 1, half = blockIdx.x & 1;
        if (t < 16) scnt[t] = 0;
        __syncthreads();
        for (int g = 0; g < GR; g++) {
            int total = gcur[(g * NBKT + bk) * 16];
            if (total > BCAPG) total = BCAPG;
            const u32* gb = gbucket + ((size_t)bk * GR + g) * BCAPG;
            for (int i = t; i < total; i += 1024) {
                u32 e = gb[i];
                int dl = (int)((e >> 16) & 31);
                if ((dl >> 4) == half) {
                    int pos = atomicAdd(&scnt[dl & 15], 1);
                    if (pos < CAP) nbr[dl & 15][pos] = (u16)(e & 0xffff);
                }
            }
        }
        __syncthreads();
        {
            int row = t >> 6, dw = t & 63;
            reinterpret_cast<u32*>(csr + ((size_t)(nb0 + row) << 7))[dw] =
                reinterpret_cast<const u32*>(&nbr[row][0])[dw];
            if (t < 16) cnt[nb0 + t] = scnt[t] > CAP ? CAP : scnt[t];
        }
        c_ = scnt[wid];
        if (c_ > CAP) c_ = CAP;
    } else {
        c_ = cnt[node];
        if (c_ > CAP) c_ = CAP;
        *reinterpret_cast<u32*>(&nbr[wid][ln << 1]) =
            *reinterpret_cast<const u32*>(csr + ((size_t)node << 7) + (ln << 1));
    }

    // ---- gather: 32 rows / iteration; each quarter owns rows {b0..b0+3, b0+16..b0+19} ----
    float va[8] = {0.f, 0.f, 0.f, 0.f, 0.f, 0.f, 0.f, 0.f};
    if (q == 0) {  // self term
        uint4 v = *reinterpret_cast<const uint4*>(gin + ((size_t)node << 7) + fo8);
        upadd(v.x, va[0], va[1]); upadd(v.y, va[2], va[3]);
        upadd(v.z, va[4], va[5]); upadd(v.w, va[6], va[7]);
    }
    int iters = (c_ + 31) >> 5;
    for (int i = 0; i < iters; i++) {
        int b0 = (i << 5) + (q << 2);
        int b1 = b0 + 16;
        ushort4 ia = *reinterpret_cast<const ushort4*>(&nbr[wid][b0]);
        ushort4 ib = *reinterpret_cast<const ushort4*>(&nbr[wid][b1]);
        int id0 = (b0 + 0 < c_) ? (int)ia.x : node;
        int id1 = (b0 + 1 < c_) ? (int)ia.y : node;
        int id2 = (b0 + 2 < c_) ? (int)ia.z : node;
        int id3 = (b0 + 3 < c_) ? (int)ia.w : node;
        int id4 = (b1 + 0 < c_) ? (int)ib.x : node;
        int id5 = (b1 + 1 < c_) ? (int)ib.y : node;
        int id6 = (b1 + 2 < c_) ? (int)ib.z : node;
        int id7 = (b1 + 3 < c_) ? (int)ib.w : node;
        uint4 v0 = *reinterpret_cast<const uint4*>(gin + ((size_t)id0 << 7) + fo8);
        uint4 v1 = *reinterpret_cast<const uint4*>(gin + ((size_t)id1 << 7) + fo8);
        uint4 v2 = *reinterpret_cast<const uint4*>(gin + ((size_t)id2 << 7) + fo8);
        uint4 v3 = *reinterpret_cast<const uint4*>(gin + ((size_t)id3 << 7) + fo8);
        uint4 v4 = *reinterpret_cast<const uint4*>(gin + ((size_t)id4 << 7) + fo8);
        uint4 v5 = *reinterpret_cast<const uint4*>(gin + ((size_t)id5 << 7) + fo8);
        uint4 v6 = *reinterpret_cast<const uint4*>(gin + ((size_t)id6 << 7) + fo8);
        uint4 v7 = *reinterpret_cast<const uint4*>(gin + ((size_t)id7 << 7) + fo8);
        if (b0 + 0 < c_) { upadd(v0.x, va[0], va[1]); upadd(v0.y, va[2], va[3]); upadd(v0.z, va[4], va[5]); upadd(v0.w, va[6], va[7]); }
        if (b0 + 1 < c_) { upadd(v1.x, va[0], va[1]); upadd(v1.y, va[2], va[3]); upadd(v1.z, va[4], va[5]); upadd(v1.w, va[6], va[7]); }
        if (b0 + 2 < c_) { upadd(v2.x, va[0], va[1]); upadd(v2.y, va[2], va[3]); upadd(v2.z, va[4], va[5]); upadd(v2.w, va[6], va[7]); }
        if (b0 + 3 < c_) { upadd(v3.x, va[0], va[1]); upadd(v3.y, va[2], va[3]); upadd(v3.z, va[4], va[5]); upadd(v3.w, va[6], va[7]); }
        if (b1 + 0 < c_) { upadd(v4.x, va[0], va[1]); upadd(v4.y, va[2], va[3]); upadd(v4.z, va[4], va[5]); upadd(v4.w, va[6], va[7]); }
        if (b1 + 1 < c_) { upadd(v5.x, va[0], va[1]); upadd(v5.y, va[2], va[3]); upadd(v5.z, va[4], va[5]); upadd(v5.w, va[6], va[7]); }
        if (b1 + 2 < c_) { upadd(v6.x, va[0], va[1]); upadd(v6.y, va[2], va[3]); upadd(v6.z, va[4], va[5]); upadd(v6.w, va[6], va[7]); }
        if (b1 + 3 < c_) { upadd(v7.x, va[0], va[1]); upadd(v7.y, va[2], va[3]); upadd(v7.z, va[4], va[5]); upadd(v7.w, va[6], va[7]); }
    }
    #pragma unroll
    for (int j = 0; j < 8; j++) {
        va[j] += __shfl_xor(va[j], 16);
        va[j] += __shfl_xor(va[j], 32);
    }
    if (ln < 16) {
        float4 bv0 = *reinterpret_cast<const float4*>(bias + fo8);
        float4 bv1 = *reinterpret_cast<const float4*>(bias + fo8 + 4);
        float4 mv0 = *reinterpret_cast<const float4*>(pd + fo8);
        float4 mv1 = *reinterpret_cast<const float4*>(pd + fo8 + 4);
        float bb[8] = {bv0.x, bv0.y, bv0.z, bv0.w, bv1.x, bv1.y, bv1.z, bv1.w};
        float mm[8] = {mv0.x, mv0.y, mv0.z, mv0.w, mv1.x, mv1.y, mv1.z, mv1.w};
        float r[8];
        #pragma unroll
        for (int j = 0; j < 8; j++) {
            float mk = fminf(fmaxf(mm[j], 0.f), 1.f);
            r[j] = fmaxf(va[j] + bb[j], 0.f) * mk;
        }
        if (LAST) {
            #pragma unroll
            for (int j = 0; j < 8; j++) sm.c.rows[wid * D + fo8 + j] = r[j];
        } else {
            u32 p0 = (u32)f2bf(r[0]) | ((u32)f2bf(r[1]) << 16);
            u32 p1 = (u32)f2bf(r[2]) | ((u32)f2bf(r[3]) << 16);
            u32 p2 = (u32)f2bf(r[4]) | ((u32)f2bf(r[5]) << 16);
            u32 p3 = (u32)f2bf(r[6]) | ((u32)f2bf(r[7]) << 16);
            *reinterpret_cast<uint4*>(&sm.A[wid * 128 + ((fq ^ (wid & 7)) << 3)]) =
                make_uint4(p0, p1, p2, p3);
        }
    }
    __syncthreads();

    if (LAST) {
        if (t < 16 * NC) {
            int n = t / NC, c = t - n * NC;
            const float* rr = &sm.c.rows[n * D];
            const float* wr = &sm.c.WlS[c * 129];
            float acc = sm.c.blS[c];
            #pragma unroll 8
            for (int k = 0; k < D; k++) acc = fmaf(rr[k], wr[k], acc);
            out[(size_t)(nb0 + n) * NC + c] = acc;
        }
        return;
    }

    // ---- gemm: A (16x128, LDS) x W^T (B-fragments direct from L2) ----
    int m = ln & 15, gq = ln >> 4;
    bf16x8 afr[4];
    if (wid < 8) {
        #pragma unroll
        for (int ks = 0; ks < 4; ks++) {
            int chunk = gq + ks * 4;
            afr[ks] = *reinterpret_cast<const bf16x8*>(&sm.A[m * 128 + ((chunk ^ (m & 7)) << 3)]);
        }
    }
    __syncthreads();  // all afr loaded before A is overlaid by Gs
    if (wid < 8) {
        f32x4v acc = (f32x4v){0.f, 0.f, 0.f, 0.f};
        int n = wid * 16 + m;
        const u16* whp = wh + (size_t)n * 128;
        const u16* wlp = wl_ + (size_t)n * 128;
        #pragma unroll
        for (int ks = 0; ks < 4; ks++) {
            bf16x8 bh = *reinterpret_cast<const bf16x8*>(whp + ks * 32 + gq * 8);
            bf16x8 bl = *reinterpret_cast<const bf16x8*>(wlp + ks * 32 + gq * 8);
            acc = __builtin_amdgcn_mfma_f32_16x16x32_bf16(afr[ks], bh, acc, 0, 0, 0);
            acc = __builtin_amdgcn_mfma_f32_16x16x32_bf16(afr[ks], bl, acc, 0, 0, 0);
        }
        u16* Gs = sm.A;  // overlay
        #pragma unroll
        for (int j = 0; j < 4; j++) {
            int mm = gq * 4 + j;
            Gs[mm * 128 + (n ^ ((mm & 7) << 4))] = f2bf(acc[j]);
        }
    }
    __syncthreads();
    if (t < 256) {
        const u16* Gs = sm.A;
        int mm = t >> 4, n0 = (t & 15) * 8;
        uint4 v = *reinterpret_cast<const uint4*>(&Gs[mm * 128 + (n0 ^ ((mm & 7) << 4))]);
        *reinterpret_cast<uint4*>(gout + (size_t)(nb0 + mm) * 128 + n0) = v;
    }
}

// ---------- launch ----------
extern "C" void kernel_launch(void* const* d_in, const int* in_sizes, int n_in,
                              void* d_out, int out_size, void* d_ws, size_t ws_size,
                              hipStream_t stream) {
    const float* x  = (const float*)d_in[0];
    const int*   ei = (const int*)d_in[1];
    const float* W0 = (const float*)d_in[2];
    const float* b0 = (const float*)d_in[3];
    const float* W1 = (const float*)d_in[4];
    const float* b1 = (const float*)d_in[5];
    const float* W2 = (const float*)d_in[6];
    const float* b2 = (const float*)d_in[7];
    const float* pd = (const float*)d_in[8];
    const float* Wl = (const float*)d_in[9];
    const float* bl = (const float*)d_in[10];

    char* ws = (char*)d_ws;
    int* cnt     = (int*)ws;                    //     40,960 B
    u16* csr     = (u16*)(ws + 40960);          //  2,560,000 B
    u16* gbA     = (u16*)(ws + 2600960);        //  2,560,000 B
    u16* gbB     = (u16*)(ws + 5160960);        //  2,560,000 B
    u32* gbucket = (u32*)(ws + 7720960);        //  3,525,632 B (live until F0 completes)
    int* gcur    = (int*)(ws + 11246592);       //    160,256 B (8*313 cursors, 64B-padded)
    u16* whi     = (u16*)(ws + 11406848);       //     98,304 B
    u16* wlo     = (u16*)(ws + 11505152);       //     98,304 B -> total ~11.6 MB

    const int* src = ei;
    const int* dst = ei + NE;

    prep_kernel<<<64, 256, 0, stream>>>((uint4*)gcur, W0, W1, W2, whi, wlo);
    phaseA<<<NBIN + 313, 256, 0, stream>>>(x, src, dst, whi, wlo, gcur, gbucket, gbA);
    fuse_kernel<true, false><<<625, 1024, 0, stream>>>(gbA, cnt, csr, gcur, gbucket, b0, pd,
                                                       whi + 16384, wlo + 16384, gbB,
                                                       nullptr, nullptr, nullptr);
    fuse_kernel<false, false><<<625, 1024, 0, stream>>>(gbB, cnt, csr, nullptr, nullptr, b1, pd,
                                                        whi + 32768, wlo + 32768, gbA,
                                                        nullptr, nullptr, nullptr);
    fuse_kernel<false, true><<<625, 1024, 0, stream>>>(gbA, cnt, csr, nullptr, nullptr, b2, pd,
                                                       nullptr, nullptr, nullptr,
                                                       Wl, bl, (float*)d_out);
}